// Round 2
// baseline (1028.763 us; speedup 1.0000x reference)
//
#include <hip/hip_runtime.h>
#include <hip/hip_bf16.h>
#include <cstdint>

// ---------------------------------------------------------------------------
// Sampled DCT2: (1) luminance + per-8x8-block 2D DCT -> [64,1,512,512]
//               (2) exact JAX threefry permutation sampling -> [64,64,250]
//
// JAX PRNG semantics: jax_threefry_partitionable = True (default since 0.4.36)
//   split(key, n):   keys[i] = (o0, o1) = threefry(key, x=(0, i))
//   random_bits(subkey, 32, (n,)): bits[j] = o0 ^ o1 of threefry(subkey,(0,j))
//   permutation(key, 4096) = 2 rounds of {key,sub = split(key);
//       bits = random_bits(sub, 32, (4096,)); x = stable_sort_by(bits, x)}
// ---------------------------------------------------------------------------

#define BATCH 64
#define HW 512
#define NBLK 4096            // 64x64 blocks per image; also permutation length
#define NSAMPLE 250
#define IMG_ELEMS (HW * HW)  // 262144

// DCT-II matrix entries, f64 literals -> f32 (matches np.float32(math.cos))
#define A0 0.35355339059327373f
#define A1 0.49039264020161522f
#define A2 0.46193976625564337f
#define A3 0.41573480615127262f
#define A4 0.35355339059327379f
#define A5 0.27778511650980111f
#define A6 0.19134171618254492f
#define A7 0.09754516100806412f

__constant__ float Qc[8][8] = {
    { A0,  A0,  A0,  A0,  A0,  A0,  A0,  A0},
    { A1,  A3,  A5,  A7, -A7, -A5, -A3, -A1},
    { A2,  A6, -A6, -A2, -A2, -A6,  A6,  A2},
    { A3, -A7, -A1, -A5,  A5,  A1,  A7, -A3},
    { A4, -A4, -A4,  A4,  A4, -A4, -A4,  A4},
    { A5, -A1,  A7,  A3, -A3, -A7,  A1, -A5},
    { A6, -A2,  A2, -A6, -A6,  A2, -A2,  A6},
    { A7, -A5,  A3, -A1,  A1, -A3,  A5, -A7},
};

__constant__ int ZIGZAG[64] = {
    0, 1, 8, 16, 9, 2, 3, 10, 17, 24, 32, 25, 18, 11, 4, 5,
    12, 19, 26, 33, 40, 48, 41, 34, 27, 20, 13, 6, 7, 14, 21, 28,
    35, 42, 49, 56, 57, 50, 43, 36, 29, 22, 15, 23, 30, 37, 44, 51,
    58, 59, 52, 45, 38, 31, 39, 46, 53, 60, 61, 54, 47, 55, 62, 63
};

// ---------------- Kernel A: luminance + 8x8 DCT ----------------------------
__global__ __launch_bounds__(256) void dct_kernel(const float* __restrict__ x,
                                                  float* __restrict__ out) {
    int g = blockIdx.x * 256 + threadIdx.x;   // one thread per 8x8 block
    int b  = g >> 12;                          // / 4096
    int rr = g & 4095;
    int ai = rr >> 6, bi = rr & 63;
    int row0 = ai * 8, col0 = bi * 8;
    size_t ib = (size_t)b * 3 * IMG_ELEMS;

    float y[8][8];
#pragma unroll
    for (int i = 0; i < 8; ++i) {
        size_t off = ib + (size_t)(row0 + i) * HW + col0;
        float4 r0 = *(const float4*)(x + off);
        float4 r1 = *(const float4*)(x + off + 4);
        float4 g0 = *(const float4*)(x + off + IMG_ELEMS);
        float4 g1 = *(const float4*)(x + off + IMG_ELEMS + 4);
        float4 b0 = *(const float4*)(x + off + 2 * IMG_ELEMS);
        float4 b1 = *(const float4*)(x + off + 2 * IMG_ELEMS + 4);
        // mimic reference: (0.299*(r*255)+0.587*(g*255)+0.114*(b*255))/255
        float R[8] = {r0.x, r0.y, r0.z, r0.w, r1.x, r1.y, r1.z, r1.w};
        float G[8] = {g0.x, g0.y, g0.z, g0.w, g1.x, g1.y, g1.z, g1.w};
        float B[8] = {b0.x, b0.y, b0.z, b0.w, b1.x, b1.y, b1.z, b1.w};
#pragma unroll
        for (int j = 0; j < 8; ++j) {
            y[i][j] = (0.299f * (R[j] * 255.0f) + 0.587f * (G[j] * 255.0f) +
                       0.114f * (B[j] * 255.0f)) / 255.0f;
        }
    }

    float t[8][8];
#pragma unroll
    for (int i = 0; i < 8; ++i)
#pragma unroll
        for (int j = 0; j < 8; ++j) {
            float s = 0.0f;
#pragma unroll
            for (int k = 0; k < 8; ++k) s += Qc[i][k] * y[k][j];
            t[i][j] = s;
        }

    size_t ob = (size_t)b * IMG_ELEMS;
#pragma unroll
    for (int i = 0; i < 8; ++i) {
        float d[8];
#pragma unroll
        for (int j = 0; j < 8; ++j) {
            float s = 0.0f;
#pragma unroll
            for (int k = 0; k < 8; ++k) s += t[i][k] * Qc[j][k];
            d[j] = s;
        }
        float4* o = (float4*)(out + ob + (size_t)(row0 + i) * HW + col0);
        o[0] = make_float4(d[0], d[1], d[2], d[3]);
        o[1] = make_float4(d[4], d[5], d[6], d[7]);
    }
}

// ---------------- Threefry-2x32 (exact JAX rounds) -------------------------
__device__ __forceinline__ uint32_t rotl32(uint32_t v, int d) {
    return (v << d) | (v >> (32 - d));
}

__device__ __forceinline__ void tf2x32(uint32_t k0, uint32_t k1,
                                       uint32_t x0, uint32_t x1,
                                       uint32_t& o0, uint32_t& o1) {
    uint32_t ks0 = k0, ks1 = k1, ks2 = k0 ^ k1 ^ 0x1BD11BDAu;
    x0 += ks0; x1 += ks1;
#define TF_R(r) { x0 += x1; x1 = rotl32(x1, r); x1 ^= x0; }
    TF_R(13) TF_R(15) TF_R(26) TF_R(6)
    x0 += ks1; x1 += ks2 + 1u;
    TF_R(17) TF_R(29) TF_R(16) TF_R(24)
    x0 += ks2; x1 += ks0 + 2u;
    TF_R(13) TF_R(15) TF_R(26) TF_R(6)
    x0 += ks0; x1 += ks1 + 3u;
    TF_R(17) TF_R(29) TF_R(16) TF_R(24)
    x0 += ks1; x1 += ks2 + 4u;
    TF_R(13) TF_R(15) TF_R(26) TF_R(6)
    x0 += ks2; x1 += ks0 + 5u;
#undef TF_R
    o0 = x0; o1 = x1;
}

// ---------------- Kernel B: permutation + gather ---------------------------
// One workgroup per (batch, coeff) pair. Stability via packed u64:
// round0: (bits << 12) | pos  (value==pos); round1: (bits<<24)|(pos<<12)|value.
__global__ __launch_bounds__(512) void sample_kernel(const float* __restrict__ img,
                                                     float* __restrict__ out2) {
    __shared__ uint64_t arr[NBLK];
    int tid = threadIdx.x;
    int gb = blockIdx.x;  // b*64 + c

    // partitionable split(key=(0,0), 4096): keys[i] = tf(key, (0, i))
    uint32_t k0, k1;
    tf2x32(0u, 0u, 0u, (uint32_t)gb, k0, k1);

    for (int round = 0; round < 2; ++round) {
        // partitionable split(key): new_key = tf(key,(0,0)), subkey = tf(key,(0,1))
        uint32_t n0, n1, s0, s1;
        tf2x32(k0, k1, 0u, 0u, n0, n1);
        tf2x32(k0, k1, 0u, 1u, s0, s1);
        k0 = n0; k1 = n1;

        __syncthreads();  // prior round's sorted arr fully written

        // partitionable random_bits(subkey, 32, (4096,)): bits[j] = o0^o1 of
        // tf(subkey, (0, j))
        for (int j = tid; j < NBLK; j += 512) {
            uint32_t o0, o1;
            tf2x32(s0, s1, 0u, (uint32_t)j, o0, o1);
            uint32_t bits = o0 ^ o1;
            if (round == 0) {
                arr[j] = ((uint64_t)bits << 12) | (uint64_t)j;
            } else {
                uint64_t v = arr[j] & 0xFFFull;
                arr[j] = ((uint64_t)bits << 24) | ((uint64_t)j << 12) | v;
            }
        }

        // in-place bitonic sort ascending (packed keys unique -> stable sort)
        for (int kk = 2; kk <= NBLK; kk <<= 1) {
            for (int jj = kk >> 1; jj > 0; jj >>= 1) {
                __syncthreads();
                for (int t = tid; t < NBLK / 2; t += 512) {
                    int i = ((t & ~(jj - 1)) << 1) | (t & (jj - 1));
                    int p = i | jj;
                    uint64_t xa = arr[i], xb = arr[p];
                    bool up = ((i & kk) == 0);
                    if ((xa > xb) == up) { arr[i] = xb; arr[p] = xa; }
                }
            }
        }
    }
    __syncthreads();

    // gather: sample[b, c, s] = dct[b, blk=perm[s]] at zigzag coeff c
    int b = gb >> 6, c = gb & 63;
    int z = ZIGZAG[c];
    int i0 = z >> 3, j0 = z & 7;
    for (int s = tid; s < NSAMPLE; s += 512) {
        int blk = (int)(arr[s] & 0xFFFull);
        int ai = blk >> 6, bi = blk & 63;
        float val = img[(size_t)b * IMG_ELEMS + (size_t)(ai * 8 + i0) * HW +
                        (bi * 8 + j0)];
        out2[(size_t)gb * NSAMPLE + s] = val;
    }
}

extern "C" void kernel_launch(void* const* d_in, const int* in_sizes, int n_in,
                              void* d_out, int out_size, void* d_ws, size_t ws_size,
                              hipStream_t stream) {
    const float* x = (const float*)d_in[0];
    float* out = (float*)d_out;
    // output 0: 64*512*512 = 16777216 floats; output 1 follows
    dct_kernel<<<(BATCH * NBLK) / 256, 256, 0, stream>>>(x, out);
    sample_kernel<<<BATCH * 64, 512, 0, stream>>>(out, out + (size_t)BATCH * IMG_ELEMS);
}

// Round 3
// 755.158 us; speedup vs baseline: 1.3623x; 1.3623x over previous
//
#include <hip/hip_runtime.h>
#include <hip/hip_bf16.h>
#include <cstdint>

// ---------------------------------------------------------------------------
// Sampled DCT2: (1) luminance + per-8x8-block 2D DCT -> [64,1,512,512]
//               (2) exact JAX threefry permutation sampling -> [64,64,250]
//
// JAX PRNG semantics: jax_threefry_partitionable = True
//   split(key, n):   keys[i] = threefry(key, (0, i))
//   random_bits(subkey, 32, (n,)): bits[j] = o0 ^ o1 of threefry(subkey,(0,j))
//   permutation = 2 rounds of {key,sub = split(key); bits = random_bits(sub);
//       x = stable_sort_by(bits, x)}
// Sort realized as stable LSD radix-256 (4 passes/round) in LDS with
// wave-ballot ranking (reads lane-strided => conflict-free).
// ---------------------------------------------------------------------------

#define BATCH 64
#define HW 512
#define NBLK 4096
#define NSAMPLE 250
#define IMG_ELEMS (HW * HW)

#define A0 0.35355339059327373f
#define A1 0.49039264020161522f
#define A2 0.46193976625564337f
#define A3 0.41573480615127262f
#define A4 0.35355339059327379f
#define A5 0.27778511650980111f
#define A6 0.19134171618254492f
#define A7 0.09754516100806412f

__constant__ float Qc[8][8] = {
    { A0,  A0,  A0,  A0,  A0,  A0,  A0,  A0},
    { A1,  A3,  A5,  A7, -A7, -A5, -A3, -A1},
    { A2,  A6, -A6, -A2, -A2, -A6,  A6,  A2},
    { A3, -A7, -A1, -A5,  A5,  A1,  A7, -A3},
    { A4, -A4, -A4,  A4,  A4, -A4, -A4,  A4},
    { A5, -A1,  A7,  A3, -A3, -A7,  A1, -A5},
    { A6, -A2,  A2, -A6, -A6,  A2, -A2,  A6},
    { A7, -A5,  A3, -A1,  A1, -A3,  A5, -A7},
};

__constant__ int ZIGZAG[64] = {
    0, 1, 8, 16, 9, 2, 3, 10, 17, 24, 32, 25, 18, 11, 4, 5,
    12, 19, 26, 33, 40, 48, 41, 34, 27, 20, 13, 6, 7, 14, 21, 28,
    35, 42, 49, 56, 57, 50, 43, 36, 29, 22, 15, 23, 30, 37, 44, 51,
    58, 59, 52, 45, 38, 31, 39, 46, 53, 60, 61, 54, 47, 55, 62, 63
};

// ---------------- Kernel A: luminance + 8x8 DCT ----------------------------
// Q*(Y*Q^T): only one 8x8 temp live at a time -> ~half the VGPRs of the
// naive (y + t) version; launch_bounds caps regs for >=4 waves/SIMD.
__global__ __launch_bounds__(256, 4) void dct_kernel(const float* __restrict__ x,
                                                     float* __restrict__ out) {
    int g = blockIdx.x * 256 + threadIdx.x;   // one thread per 8x8 block
    int b  = g >> 12;
    int rr = g & 4095;
    int ai = rr >> 6, bi = rr & 63;
    int row0 = ai * 8, col0 = bi * 8;
    size_t ib = (size_t)b * 3 * IMG_ELEMS;

    float u[8][8];   // u = Y * Q^T, built row by row
#pragma unroll
    for (int i = 0; i < 8; ++i) {
        size_t off = ib + (size_t)(row0 + i) * HW + col0;
        float4 r0 = *(const float4*)(x + off);
        float4 r1 = *(const float4*)(x + off + 4);
        float4 g0 = *(const float4*)(x + off + IMG_ELEMS);
        float4 g1 = *(const float4*)(x + off + IMG_ELEMS + 4);
        float4 b0 = *(const float4*)(x + off + 2 * IMG_ELEMS);
        float4 b1 = *(const float4*)(x + off + 2 * IMG_ELEMS + 4);
        float R[8] = {r0.x, r0.y, r0.z, r0.w, r1.x, r1.y, r1.z, r1.w};
        float G[8] = {g0.x, g0.y, g0.z, g0.w, g1.x, g1.y, g1.z, g1.w};
        float B[8] = {b0.x, b0.y, b0.z, b0.w, b1.x, b1.y, b1.z, b1.w};
        float y[8];
#pragma unroll
        for (int j = 0; j < 8; ++j)
            y[j] = (0.299f * (R[j] * 255.0f) + 0.587f * (G[j] * 255.0f) +
                    0.114f * (B[j] * 255.0f)) / 255.0f;
#pragma unroll
        for (int j = 0; j < 8; ++j) {
            float s = 0.0f;
#pragma unroll
            for (int k = 0; k < 8; ++k) s += y[k] * Qc[j][k];
            u[i][j] = s;
        }
    }

    size_t ob = (size_t)b * IMG_ELEMS;
#pragma unroll
    for (int i = 0; i < 8; ++i) {
        float d[8];
#pragma unroll
        for (int j = 0; j < 8; ++j) {
            float s = 0.0f;
#pragma unroll
            for (int k = 0; k < 8; ++k) s += Qc[i][k] * u[k][j];
            d[j] = s;
        }
        float4* o = (float4*)(out + ob + (size_t)(row0 + i) * HW + col0);
        o[0] = make_float4(d[0], d[1], d[2], d[3]);
        o[1] = make_float4(d[4], d[5], d[6], d[7]);
    }
}

// ---------------- Threefry-2x32 (exact JAX rounds) -------------------------
__device__ __forceinline__ uint32_t rotl32(uint32_t v, int d) {
    return (v << d) | (v >> (32 - d));
}

__device__ __forceinline__ void tf2x32(uint32_t k0, uint32_t k1,
                                       uint32_t x0, uint32_t x1,
                                       uint32_t& o0, uint32_t& o1) {
    uint32_t ks0 = k0, ks1 = k1, ks2 = k0 ^ k1 ^ 0x1BD11BDAu;
    x0 += ks0; x1 += ks1;
#define TF_R(r) { x0 += x1; x1 = rotl32(x1, r); x1 ^= x0; }
    TF_R(13) TF_R(15) TF_R(26) TF_R(6)
    x0 += ks1; x1 += ks2 + 1u;
    TF_R(17) TF_R(29) TF_R(16) TF_R(24)
    x0 += ks2; x1 += ks0 + 2u;
    TF_R(13) TF_R(15) TF_R(26) TF_R(6)
    x0 += ks0; x1 += ks1 + 3u;
    TF_R(17) TF_R(29) TF_R(16) TF_R(24)
    x0 += ks1; x1 += ks2 + 4u;
    TF_R(13) TF_R(15) TF_R(26) TF_R(6)
    x0 += ks2; x1 += ks0 + 5u;
#undef TF_R
    o0 = x0; o1 = x1;
}

// ---------------- Kernel B: permutation via LDS radix sort + gather --------
// One workgroup (512 thr = 8 waves) per (batch, coeff). Keys u32 (random
// bits), payload u16 (position/value); stable radix-256 LSD, 4 passes/round.
// Wave w owns elements [w*512, (w+1)*512); lane-strided => conflict-free
// reads. Stable dest = bases[digit-major scan] + per-(wave,digit) run +
// within-wave ballot rank.
__global__ __launch_bounds__(512, 4) void sample_kernel(const float* __restrict__ img,
                                                        float* __restrict__ out2) {
    __shared__ uint32_t kbuf[2][NBLK];    // 32 KB
    __shared__ uint16_t vbuf[2][NBLK];    // 16 KB
    __shared__ uint16_t whist[2048];      // [wave][256] histogram, 4 KB
    __shared__ uint16_t wrun[2048];       // [wave][256] running count, 4 KB
    __shared__ uint16_t bases[2048];      // digit-major [d][w], 4 KB
    __shared__ uint32_t wtots[8];

    const int tid = threadIdx.x;
    const int w = tid >> 6;
    const int lane = tid & 63;
    const uint64_t lt = (lane == 0) ? 0ull : (~0ull >> (64 - lane));
    const int gb = blockIdx.x;  // b*64 + c

    // partitionable split(key(0), 4096)[gb]
    uint32_t k0, k1;
    tf2x32(0u, 0u, 0u, (uint32_t)gb, k0, k1);

    for (int round = 0; round < 2; ++round) {
        // key, subkey = split(key)
        uint32_t n0, n1, s0, s1;
        tf2x32(k0, k1, 0u, 0u, n0, n1);
        tf2x32(k0, k1, 0u, 1u, s0, s1);
        k0 = n0; k1 = n1;

        __syncthreads();
        // fill keys; round 0 also inits payload = position. Round 1 keeps
        // vbuf[0] (= round-0 sorted values) as payload in place.
        for (int i = 0; i < 8; ++i) {
            int j = tid + i * 512;
            uint32_t o0, o1;
            tf2x32(s0, s1, 0u, (uint32_t)j, o0, o1);
            kbuf[0][j] = o0 ^ o1;
            if (round == 0) vbuf[0][j] = (uint16_t)j;
        }

        for (int p = 0; p < 4; ++p) {
            const int sh = p * 8;
            const int s = p & 1, dsb = s ^ 1;
#pragma unroll
            for (int q = 0; q < 4; ++q) {
                whist[tid + q * 512] = 0;
                wrun[tid + q * 512] = 0;
            }
            __syncthreads();

            // phase 1: load + per-wave histogram via ballot leaders
            uint32_t keys[8], vals[8];
            uint64_t msk[8];
#pragma unroll
            for (int e = 0; e < 8; ++e) {
                int j = w * 512 + e * 64 + lane;
                uint32_t kk = kbuf[s][j];
                keys[e] = kk;
                vals[e] = vbuf[s][j];
                int d = (int)((kk >> sh) & 255u);
                uint64_t m = ~0ull;
#pragma unroll
                for (int bb = 0; bb < 8; ++bb) {
                    uint64_t bal = __ballot((d >> bb) & 1);
                    m &= ((d >> bb) & 1) ? bal : ~bal;
                }
                msk[e] = m;
                if ((m & lt) == 0)  // leader of this digit group
                    whist[w * 256 + d] =
                        (uint16_t)(whist[w * 256 + d] + (uint16_t)__popcll(m));
            }
            __syncthreads();

            // exclusive scan of 2048 digit-major counts -> bases
            uint32_t pre[4], ssum = 0;
            const int i0 = tid * 4;
#pragma unroll
            for (int q = 0; q < 4; ++q) {
                int i = i0 + q;
                uint32_t v = whist[(i & 7) * 256 + (i >> 3)];
                pre[q] = ssum; ssum += v;
            }
            uint32_t sc = ssum;
#pragma unroll
            for (int off = 1; off < 64; off <<= 1) {
                uint32_t t = __shfl_up(sc, off);
                if (lane >= off) sc += t;
            }
            if (lane == 63) wtots[w] = sc;
            __syncthreads();
            uint32_t woff = 0;
            for (int ww = 0; ww < w; ++ww) woff += wtots[ww];
            uint32_t ex = woff + sc - ssum;
#pragma unroll
            for (int q = 0; q < 4; ++q) bases[i0 + q] = (uint16_t)(ex + pre[q]);
            __syncthreads();

            // phase 2: stable scatter
#pragma unroll
            for (int e = 0; e < 8; ++e) {
                uint32_t kk = keys[e];
                int d = (int)((kk >> sh) & 255u);
                uint64_t m = msk[e];
                int below = __popcll(m & lt);
                uint32_t base = bases[d * 8 + w];
                uint32_t run = wrun[w * 256 + d];
                uint32_t dest = base + run + (uint32_t)below;
                kbuf[dsb][dest] = kk;
                vbuf[dsb][dest] = (uint16_t)vals[e];
                if (below == 0)
                    wrun[w * 256 + d] = (uint16_t)(run + (uint32_t)__popcll(m));
            }
            __syncthreads();
        }
        // 4 passes: data back in buffer 0
    }

    // gather: sample[b, c, s] = dct[b, blk=perm[s]] at zigzag coeff c
    int b = gb >> 6, c = gb & 63;
    int z = ZIGZAG[c];
    int i0z = z >> 3, j0z = z & 7;
    for (int si = tid; si < NSAMPLE; si += 512) {
        int blk = (int)vbuf[0][si];
        int ai = blk >> 6, bi = blk & 63;
        float val = img[(size_t)b * IMG_ELEMS + (size_t)(ai * 8 + i0z) * HW +
                        (bi * 8 + j0z)];
        out2[(size_t)gb * NSAMPLE + si] = val;
    }
}

extern "C" void kernel_launch(void* const* d_in, const int* in_sizes, int n_in,
                              void* d_out, int out_size, void* d_ws, size_t ws_size,
                              hipStream_t stream) {
    const float* x = (const float*)d_in[0];
    float* out = (float*)d_out;
    dct_kernel<<<(BATCH * NBLK) / 256, 256, 0, stream>>>(x, out);
    sample_kernel<<<BATCH * 64, 512, 0, stream>>>(out, out + (size_t)BATCH * IMG_ELEMS);
}

// Round 4
// 609.896 us; speedup vs baseline: 1.6868x; 1.2382x over previous
//
#include <hip/hip_runtime.h>
#include <hip/hip_bf16.h>
#include <cstdint>

// ---------------------------------------------------------------------------
// Sampled DCT2: (1) luminance + per-8x8-block 2D DCT -> [64,1,512,512]
//               (2) exact JAX threefry permutation sampling -> [64,64,250]
//
// JAX PRNG semantics: jax_threefry_partitionable = True
//   split(key, n):   keys[i] = threefry(key, (0, i))
//   random_bits(subkey, 32, (n,)): bits[j] = o0 ^ o1 of threefry(subkey,(0,j))
//   permutation = 2 rounds of {key,sub = split(key); bits = random_bits(sub);
//       x = stable_sort_by(bits, x)}
// Round 0: full stable LSD radix-256 sort (4 passes) in LDS.
// Round 1: only the first 250 sorted entries are consumed -> top-byte
//   histogram selection + bitonic sort of <=512 candidates (exact + stable).
// ---------------------------------------------------------------------------

#define BATCH 64
#define HW 512
#define NBLK 4096
#define NSAMPLE 250
#define IMG_ELEMS (HW * HW)

#define A0 0.35355339059327373f
#define A1 0.49039264020161522f
#define A2 0.46193976625564337f
#define A3 0.41573480615127262f
#define A4 0.35355339059327379f
#define A5 0.27778511650980111f
#define A6 0.19134171618254492f
#define A7 0.09754516100806412f

__constant__ float Qc[8][8] = {
    { A0,  A0,  A0,  A0,  A0,  A0,  A0,  A0},
    { A1,  A3,  A5,  A7, -A7, -A5, -A3, -A1},
    { A2,  A6, -A6, -A2, -A2, -A6,  A6,  A2},
    { A3, -A7, -A1, -A5,  A5,  A1,  A7, -A3},
    { A4, -A4, -A4,  A4,  A4, -A4, -A4,  A4},
    { A5, -A1,  A7,  A3, -A3, -A7,  A1, -A5},
    { A6, -A2,  A2, -A6, -A6,  A2, -A2,  A6},
    { A7, -A5,  A3, -A1,  A1, -A3,  A5, -A7},
};

__constant__ int ZIGZAG[64] = {
    0, 1, 8, 16, 9, 2, 3, 10, 17, 24, 32, 25, 18, 11, 4, 5,
    12, 19, 26, 33, 40, 48, 41, 34, 27, 20, 13, 6, 7, 14, 21, 28,
    35, 42, 49, 56, 57, 50, 43, 36, 29, 22, 15, 23, 30, 37, 44, 51,
    58, 59, 52, 45, 38, 31, 39, 46, 53, 60, 61, 54, 47, 55, 62, 63
};

// ---------------- Kernel A: luminance + 8x8 DCT ----------------------------
// Streaming form: acc = Q*Y built row-by-row (one input row live at a time),
// then D = acc*Q^T stored row-by-row. No min-waves bound: (256,4) forced
// spills in R3 (dct est. 215->255us). Let the allocator pick.
__global__ __launch_bounds__(256) void dct_kernel(const float* __restrict__ x,
                                                  float* __restrict__ out) {
    int g = blockIdx.x * 256 + threadIdx.x;   // one thread per 8x8 block
    int b  = g >> 12;
    int rr = g & 4095;
    int ai = rr >> 6, bi = rr & 63;
    int row0 = ai * 8, col0 = bi * 8;
    size_t ib = (size_t)b * 3 * IMG_ELEMS;

    float acc[8][8];  // Q * Y
#pragma unroll
    for (int k = 0; k < 8; ++k) {
        size_t off = ib + (size_t)(row0 + k) * HW + col0;
        float4 r0 = *(const float4*)(x + off);
        float4 r1 = *(const float4*)(x + off + 4);
        float4 g0 = *(const float4*)(x + off + IMG_ELEMS);
        float4 g1 = *(const float4*)(x + off + IMG_ELEMS + 4);
        float4 b0 = *(const float4*)(x + off + 2 * IMG_ELEMS);
        float4 b1 = *(const float4*)(x + off + 2 * IMG_ELEMS + 4);
        float R[8] = {r0.x, r0.y, r0.z, r0.w, r1.x, r1.y, r1.z, r1.w};
        float G[8] = {g0.x, g0.y, g0.z, g0.w, g1.x, g1.y, g1.z, g1.w};
        float B[8] = {b0.x, b0.y, b0.z, b0.w, b1.x, b1.y, b1.z, b1.w};
        float y[8];
#pragma unroll
        for (int j = 0; j < 8; ++j)
            y[j] = (0.299f * (R[j] * 255.0f) + 0.587f * (G[j] * 255.0f) +
                    0.114f * (B[j] * 255.0f)) / 255.0f;
#pragma unroll
        for (int i = 0; i < 8; ++i) {
            float q = Qc[i][k];
#pragma unroll
            for (int j = 0; j < 8; ++j)
                acc[i][j] = (k == 0) ? q * y[j] : acc[i][j] + q * y[j];
        }
    }

    size_t ob = (size_t)b * IMG_ELEMS;
#pragma unroll
    for (int i = 0; i < 8; ++i) {
        float d[8];
#pragma unroll
        for (int j = 0; j < 8; ++j) {
            float s = 0.0f;
#pragma unroll
            for (int k = 0; k < 8; ++k) s += acc[i][k] * Qc[j][k];
            d[j] = s;
        }
        float4* o = (float4*)(out + ob + (size_t)(row0 + i) * HW + col0);
        o[0] = make_float4(d[0], d[1], d[2], d[3]);
        o[1] = make_float4(d[4], d[5], d[6], d[7]);
    }
}

// ---------------- Threefry-2x32 (exact JAX rounds) -------------------------
__device__ __forceinline__ uint32_t rotl32(uint32_t v, int d) {
    return (v << d) | (v >> (32 - d));
}

__device__ __forceinline__ void tf2x32(uint32_t k0, uint32_t k1,
                                       uint32_t x0, uint32_t x1,
                                       uint32_t& o0, uint32_t& o1) {
    uint32_t ks0 = k0, ks1 = k1, ks2 = k0 ^ k1 ^ 0x1BD11BDAu;
    x0 += ks0; x1 += ks1;
#define TF_R(r) { x0 += x1; x1 = rotl32(x1, r); x1 ^= x0; }
    TF_R(13) TF_R(15) TF_R(26) TF_R(6)
    x0 += ks1; x1 += ks2 + 1u;
    TF_R(17) TF_R(29) TF_R(16) TF_R(24)
    x0 += ks2; x1 += ks0 + 2u;
    TF_R(13) TF_R(15) TF_R(26) TF_R(6)
    x0 += ks0; x1 += ks1 + 3u;
    TF_R(17) TF_R(29) TF_R(16) TF_R(24)
    x0 += ks1; x1 += ks2 + 4u;
    TF_R(13) TF_R(15) TF_R(26) TF_R(6)
    x0 += ks2; x1 += ks0 + 5u;
#undef TF_R
    o0 = x0; o1 = x1;
}

// ---------------- Kernel B: permutation + gather ---------------------------
__global__ __launch_bounds__(512) void sample_kernel(const float* __restrict__ img,
                                                     float* __restrict__ out2) {
    __shared__ __align__(16) uint32_t kbuf[2][NBLK];  // 32 KB
    __shared__ uint16_t vbuf[2][NBLK];                // 16 KB
    __shared__ uint16_t whist[2048];                  // [wave][256]
    __shared__ uint16_t wrun[2048];
    __shared__ uint16_t bases[2048];                  // digit-major [d][w]
    __shared__ uint32_t wtots[8];
    __shared__ uint32_t hist256[256];
    __shared__ uint32_t cntsh;
    __shared__ int Tsh;
    uint64_t* cand = (uint64_t*)kbuf[1];  // free after round 0 (ends in buf 0)

    const int tid = threadIdx.x;
    const int w = tid >> 6;
    const int lane = tid & 63;
    const uint64_t lt = (lane == 0) ? 0ull : (~0ull >> (64 - lane));
    const int gb = blockIdx.x;  // b*64 + c

    // partitionable split(key(0), 4096)[gb]
    uint32_t k0, k1;
    tf2x32(0u, 0u, 0u, (uint32_t)gb, k0, k1);

    // ======================= ROUND 0: full radix sort ======================
    uint32_t n0, n1, s0, s1;
    tf2x32(k0, k1, 0u, 0u, n0, n1);
    tf2x32(k0, k1, 0u, 1u, s0, s1);
    k0 = n0; k1 = n1;

    for (int i = 0; i < 8; ++i) {
        int j = tid + i * 512;
        uint32_t o0, o1;
        tf2x32(s0, s1, 0u, (uint32_t)j, o0, o1);
        kbuf[0][j] = o0 ^ o1;
        vbuf[0][j] = (uint16_t)j;
    }

    for (int p = 0; p < 4; ++p) {
        const int sh = p * 8;
        const int s = p & 1, dsb = s ^ 1;
#pragma unroll
        for (int q = 0; q < 4; ++q) {
            whist[tid + q * 512] = 0;
            wrun[tid + q * 512] = 0;
        }
        __syncthreads();

        // phase 1: per-wave histogram via ballot leaders
        uint32_t keys[8], vals[8];
        uint64_t msk[8];
#pragma unroll
        for (int e = 0; e < 8; ++e) {
            int j = w * 512 + e * 64 + lane;
            uint32_t kk = kbuf[s][j];
            keys[e] = kk;
            vals[e] = vbuf[s][j];
            int d = (int)((kk >> sh) & 255u);
            uint64_t m = ~0ull;
#pragma unroll
            for (int bb = 0; bb < 8; ++bb) {
                uint64_t bal = __ballot((d >> bb) & 1);
                m &= ((d >> bb) & 1) ? bal : ~bal;
            }
            msk[e] = m;
            if ((m & lt) == 0)
                whist[w * 256 + d] =
                    (uint16_t)(whist[w * 256 + d] + (uint16_t)__popcll(m));
        }
        __syncthreads();

        // exclusive scan of 2048 digit-major counts -> bases
        uint32_t pre[4], ssum = 0;
        const int i0 = tid * 4;
#pragma unroll
        for (int q = 0; q < 4; ++q) {
            int i = i0 + q;
            uint32_t v = whist[(i & 7) * 256 + (i >> 3)];
            pre[q] = ssum; ssum += v;
        }
        uint32_t sc = ssum;
#pragma unroll
        for (int off = 1; off < 64; off <<= 1) {
            uint32_t t = __shfl_up(sc, off);
            if (lane >= off) sc += t;
        }
        if (lane == 63) wtots[w] = sc;
        __syncthreads();
        uint32_t woff = 0;
        for (int ww = 0; ww < w; ++ww) woff += wtots[ww];
        uint32_t ex = woff + sc - ssum;
#pragma unroll
        for (int q = 0; q < 4; ++q) bases[i0 + q] = (uint16_t)(ex + pre[q]);
        __syncthreads();

        // phase 2: stable scatter
#pragma unroll
        for (int e = 0; e < 8; ++e) {
            uint32_t kk = keys[e];
            int d = (int)((kk >> sh) & 255u);
            uint64_t m = msk[e];
            int below = __popcll(m & lt);
            uint32_t base = bases[d * 8 + w];
            uint32_t run = wrun[w * 256 + d];
            uint32_t dest = base + run + (uint32_t)below;
            kbuf[dsb][dest] = kk;
            vbuf[dsb][dest] = (uint16_t)vals[e];
            if (below == 0)
                wrun[w * 256 + d] = (uint16_t)(run + (uint32_t)__popcll(m));
        }
        __syncthreads();
    }
    // round 0 result: kbuf[0]/vbuf[0] (vbuf[0] = permuted positions)

    // ================= ROUND 1: select smallest 250 (stable) ===============
    tf2x32(k0, k1, 0u, 0u, n0, n1);
    tf2x32(k0, k1, 0u, 1u, s0, s1);

    if (tid < 256) hist256[tid] = 0;
    if (tid == 0) cntsh = 0;
    __syncthreads();

    uint32_t myk[8];
#pragma unroll
    for (int e = 0; e < 8; ++e) {
        int j = tid + e * 512;
        uint32_t o0, o1;
        tf2x32(s0, s1, 0u, (uint32_t)j, o0, o1);
        uint32_t kk = o0 ^ o1;
        myk[e] = kk;
        atomicAdd(&hist256[kk >> 24], 1u);
    }
    __syncthreads();

    // inclusive scan of hist256 across 256 threads (4 waves + carry)
    uint32_t sc2 = 0;
    if (tid < 256) {
        sc2 = hist256[tid];
#pragma unroll
        for (int off = 1; off < 64; off <<= 1) {
            uint32_t t = __shfl_up(sc2, off);
            if (lane >= off) sc2 += t;
        }
        if (lane == 63) wtots[w] = sc2;
    }
    __syncthreads();
    if (tid < 256) {
        uint32_t carry = 0;
        for (int ww = 0; ww < w; ++ww) carry += wtots[ww];
        hist256[tid] = sc2 + carry;  // cumulative count through bucket tid
    }
    __syncthreads();
    if (tid < 256) {
        uint32_t c = hist256[tid];
        uint32_t cp = tid ? hist256[tid - 1] : 0u;
        if (c >= NSAMPLE && cp < NSAMPLE) Tsh = tid;  // exactly one writer
    }
    __syncthreads();
    const int T = Tsh;

    // compact candidates (bucket <= T); order fixed later by full sort
#pragma unroll
    for (int e = 0; e < 8; ++e) {
        uint32_t kk = myk[e];
        if ((int)(kk >> 24) <= T) {
            uint32_t slot = atomicAdd(&cntsh, 1u);
            if (slot < 512)
                cand[slot] = ((uint64_t)kk << 12) | (uint32_t)(tid + e * 512);
        }
    }
    __syncthreads();
    uint32_t cnt = cntsh;
    if (tid < 512 && tid >= cnt) cand[tid] = ~0ull;  // pad with +inf

    // bitonic sort of 512 packed (key<<12 | pos) -> exact stable order
    for (int kk2 = 2; kk2 <= 512; kk2 <<= 1) {
        for (int jj = kk2 >> 1; jj > 0; jj >>= 1) {
            __syncthreads();
            if (tid < 256) {
                int i = ((tid & ~(jj - 1)) << 1) | (tid & (jj - 1));
                int p = i | jj;
                uint64_t xa = cand[i], xb = cand[p];
                bool up = ((i & kk2) == 0);
                if ((xa > xb) == up) { cand[i] = xb; cand[p] = xa; }
            }
        }
    }
    __syncthreads();

    // gather: sample[b, c, s] = dct[b, blk] at zigzag coeff c
    int b = gb >> 6, c = gb & 63;
    int z = ZIGZAG[c];
    int i0z = z >> 3, j0z = z & 7;
    if (tid < NSAMPLE) {
        int pos = (int)(cand[tid] & 0xFFFull);
        int blk = (int)vbuf[0][pos];
        int ai = blk >> 6, bi = blk & 63;
        float val = img[(size_t)b * IMG_ELEMS + (size_t)(ai * 8 + i0z) * HW +
                        (bi * 8 + j0z)];
        out2[(size_t)gb * NSAMPLE + tid] = val;
    }
}

extern "C" void kernel_launch(void* const* d_in, const int* in_sizes, int n_in,
                              void* d_out, int out_size, void* d_ws, size_t ws_size,
                              hipStream_t stream) {
    const float* x = (const float*)d_in[0];
    float* out = (float*)d_out;
    dct_kernel<<<(BATCH * NBLK) / 256, 256, 0, stream>>>(x, out);
    sample_kernel<<<BATCH * 64, 512, 0, stream>>>(out, out + (size_t)BATCH * IMG_ELEMS);
}